// Round 1
// baseline (603.463 us; speedup 1.0000x reference)
//
#include <hip/hip_runtime.h>

#define TOK   32768
#define DM    768
#define LSEQ  4096
#define NC    32
#define CL    128
#define NCHAIN 6144

typedef __bf16 bf16x8 __attribute__((ext_vector_type(8)));
typedef float  f32x4  __attribute__((ext_vector_type(4)));
typedef unsigned short u16;

__device__ __forceinline__ u16 f2bf(float f) {
  unsigned u = __builtin_bit_cast(unsigned, f);
  u += 0x7fffu + ((u >> 16) & 1u);
  return (u16)(u >> 16);
}
__device__ __forceinline__ float bf2f(u16 h) {
  unsigned u = ((unsigned)h) << 16;
  return __builtin_bit_cast(float, u);
}

#define GLOAD_LDS16(g, l) __builtin_amdgcn_global_load_lds( \
    (const __attribute__((address_space(1))) void*)(g),     \
    (__attribute__((address_space(3))) void*)(l), 16, 0, 0)

// ---------------- weight convert (+zero pad) fp32 -> bf16 ----------------
__global__ void cvt_pad_k(const float* __restrict__ src, u16* __restrict__ dst,
                          int rows, int cols, int dcols, int n) {
  int i = blockIdx.x * 256 + threadIdx.x;
  if (i >= n) return;
  int r = i / dcols, c = i % dcols;
  dst[i] = (r < rows && c < cols) ? f2bf(src[r * cols + c]) : (u16)0;
}

// ---------------- RMSNorm: x (fp32) -> xn (bf16) ----------------
__global__ __launch_bounds__(256)
void rmsnorm_k(const float* __restrict__ x, const float* __restrict__ w,
               u16* __restrict__ xnb) {
  long t = blockIdx.x;
  const float* xr = x + t * DM;
  int tid = threadIdx.x;
  float v0 = xr[tid], v1 = xr[tid + 256], v2 = xr[tid + 512];
  float s = v0 * v0 + v1 * v1 + v2 * v2;
#pragma unroll
  for (int o = 32; o; o >>= 1) s += __shfl_down(s, o, 64);
  __shared__ float red[4];
  if ((tid & 63) == 0) red[tid >> 6] = s;
  __syncthreads();
  float tot = red[0] + red[1] + red[2] + red[3];
  float sc = rsqrtf(tot * (1.f / 768.f) + 1e-6f);
  xnb[t * DM + tid]       = f2bf(v0 * sc * w[tid]);
  xnb[t * DM + tid + 256] = f2bf(v1 * sc * w[tid + 256]);
  xnb[t * DM + tid + 512] = f2bf(v2 * sc * w[tid + 512]);
}

// ---------------- MFMA GEMM: C[m][n] = sum_k A[m][k]*B[n][k] ----------------
// A: (M x K) bf16 row stride lda; B: (N x K) bf16 row stride ldb. K % 32 == 0.
// BM=BN=128, BK=32, 256 threads = 4 waves (2x2), each wave 64x64 (4x4 frags).
// EPI: 0 plain fp32 store; 1 in_proj (conv+silu -> o0 bf16, silu(z) -> o1 bf16);
//      2 dt_proj (bias+softplus -> C fp32); 3 x_proj (bf16 delta_raw -> o0, Bm/C -> C[t*2+..])
template <int EPI>
__global__ __launch_bounds__(256)
void gemm_bt(const u16* __restrict__ A, int lda,
             const u16* __restrict__ B, int ldb,
             int K,
             float* __restrict__ C, int ldc,
             const float* __restrict__ w0, const float* __restrict__ w1,
             u16* __restrict__ o0, u16* __restrict__ o1) {
  __shared__ __align__(16) u16 smA[128 * 32];
  __shared__ __align__(16) u16 smB[128 * 32];
  const int tid = threadIdx.x;
  const int lane = tid & 63;
  const int wid = tid >> 6;
  const long rowBase = (long)blockIdx.y * 128;
  const int colBase = blockIdx.x * 128;

  const int wr = (wid >> 1) * 64;
  const int wc = (wid & 1) * 64;
  const int lr = lane & 15;
  const int kc = lane >> 4;

  f32x4 acc[4][4] = {};

  for (int kt = 0; kt < K; kt += 32) {
#pragma unroll
    for (int i = 0; i < 2; ++i) {
      int c = tid + i * 256;
      int row = c >> 2, kk = (c & 3) * 8;
      const u16* gpA = A + (rowBase + row) * (long)lda + kt + kk;
      const u16* gpB = B + (long)(colBase + row) * ldb + kt + kk;
      GLOAD_LDS16(gpA, &smA[c * 8]);
      GLOAD_LDS16(gpB, &smB[c * 8]);
    }
    __syncthreads();
    bf16x8 af[4], bfr[4];
#pragma unroll
    for (int m = 0; m < 4; ++m)
      af[m] = *(const bf16x8*)&smA[(wr + m * 16 + lr) * 32 + kc * 8];
#pragma unroll
    for (int n = 0; n < 4; ++n)
      bfr[n] = *(const bf16x8*)&smB[(wc + n * 16 + lr) * 32 + kc * 8];
#pragma unroll
    for (int m = 0; m < 4; ++m)
#pragma unroll
      for (int n = 0; n < 4; ++n)
        acc[m][n] = __builtin_amdgcn_mfma_f32_16x16x32_bf16(af[m], bfr[n], acc[m][n], 0, 0, 0);
    __syncthreads();
  }

#pragma unroll
  for (int m = 0; m < 4; ++m)
#pragma unroll
    for (int n = 0; n < 4; ++n)
#pragma unroll
      for (int j = 0; j < 4; ++j) {
        long grow = rowBase + wr + m * 16 + kc * 4 + j;
        int gcol = colBase + wc + n * 16 + lr;
        float v = acc[m][n][j];
        if (EPI == 0) {
          C[grow * ldc + gcol] = v;
        } else if (EPI == 1) {
          if (gcol < DM) {
            float t = v * w0[gcol] + w1[gcol];
            float s = t / (1.f + __expf(-t));
            o0[grow * DM + gcol] = f2bf(s);
          } else {
            float s = v / (1.f + __expf(-v));
            o1[grow * DM + (gcol - DM)] = f2bf(s);
          }
        } else if (EPI == 2) {
          float t = v + w0[gcol];
          float d = (t > 20.f) ? t : log1pf(__expf(t));
          C[grow * ldc + gcol] = d;
        } else {  // EPI == 3
          if (gcol < 64) o0[grow * 64 + gcol] = (gcol < 48) ? f2bf(v) : (u16)0;
          if (gcol == 48) C[grow * 2 + 0] = v;
          if (gcol == 49) C[grow * 2 + 1] = v;
        }
      }
}

// ---------------- selective scan (N_STATE=1), chunked 3-pass ----------------
__global__ __launch_bounds__(256)
void scan1_k(const float* __restrict__ delta, const u16* __restrict__ xcb,
             const float* __restrict__ bmc, const float* __restrict__ A_log,
             float* __restrict__ aprod, float* __restrict__ hend) {
  int e = blockIdx.x * 256 + threadIdx.x;
  int b = blockIdx.y;
  int c = blockIdx.z;
  float Ae = -__expf(A_log[e]);
  float ap = 1.f, h = 0.f;
  long base = (long)b * LSEQ + (long)c * CL;
  for (int i = 0; i < CL; ++i) {
    long t = base + i;
    float d = delta[t * DM + e];
    float xc = bf2f(xcb[t * DM + e]);
    float Bm = bmc[t * 2];
    float a = __expf(d * Ae);
    ap *= a;
    h = a * h + d * Bm * xc;
  }
  int chain = b * DM + e;
  aprod[c * NCHAIN + chain] = ap;
  hend[c * NCHAIN + chain] = h;
}

__global__ __launch_bounds__(256)
void scan2_k(const float* __restrict__ aprod, const float* __restrict__ hend,
             float* __restrict__ carry) {
  int chain = blockIdx.x * 256 + threadIdx.x;
  float h = 0.f;
  for (int c = 0; c < NC; ++c) {
    carry[c * NCHAIN + chain] = h;
    h = aprod[c * NCHAIN + chain] * h + hend[c * NCHAIN + chain];
  }
}

__global__ __launch_bounds__(256)
void scan3_k(const float* __restrict__ delta, const u16* __restrict__ xcb,
             const float* __restrict__ bmc, const float* __restrict__ A_log,
             const float* __restrict__ Dp, const u16* __restrict__ szb,
             const float* __restrict__ carry, u16* __restrict__ ybf) {
  int e = blockIdx.x * 256 + threadIdx.x;
  int b = blockIdx.y;
  int c = blockIdx.z;
  float Ae = -__expf(A_log[e]);
  float De = Dp[e];
  int chain = b * DM + e;
  float h = carry[c * NCHAIN + chain];
  long base = (long)b * LSEQ + (long)c * CL;
  for (int i = 0; i < CL; ++i) {
    long t = base + i;
    float d = delta[t * DM + e];
    float xc = bf2f(xcb[t * DM + e]);
    float Bm = bmc[t * 2];
    float Cc = bmc[t * 2 + 1];
    float a = __expf(d * Ae);
    h = a * h + d * Bm * xc;
    float y = h * Cc + De * xc;
    float sz = bf2f(szb[t * DM + e]);
    ybf[t * DM + e] = f2bf(y * sz);
  }
}

// ---------------- launch ----------------
extern "C" void kernel_launch(void* const* d_in, const int* in_sizes, int n_in,
                              void* d_out, int out_size, void* d_ws, size_t ws_size,
                              hipStream_t stream) {
  const float* x         = (const float*)d_in[0];
  const float* rms_w     = (const float*)d_in[1];
  const float* in_proj_w = (const float*)d_in[2];
  const float* conv_w    = (const float*)d_in[3];
  const float* conv_b    = (const float*)d_in[4];
  const float* x_proj_w  = (const float*)d_in[5];
  const float* dt_proj_w = (const float*)d_in[6];
  const float* dt_proj_b = (const float*)d_in[7];
  const float* A_log     = (const float*)d_in[8];
  const float* Dp        = (const float*)d_in[9];
  const float* out_proj_w= (const float*)d_in[10];
  float* out = (float*)d_out;

  char* ws = (char*)d_ws;
  size_t off = 0;
  auto alloc = [&](size_t bytes) -> void* {
    void* p = ws + off;
    off += (bytes + 255) & ~(size_t)255;
    return p;
  };
  u16*   xnb   = (u16*)alloc((size_t)TOK * DM * 2);
  u16*   xcb   = (u16*)alloc((size_t)TOK * DM * 2);
  u16*   szb   = (u16*)alloc((size_t)TOK * DM * 2);
  u16*   ybf   = (u16*)alloc((size_t)TOK * DM * 2);
  u16*   dbcb  = (u16*)alloc((size_t)TOK * 64 * 2);
  float* bmc   = (float*)alloc((size_t)TOK * 2 * 4);
  float* delta = (float*)alloc((size_t)TOK * DM * 4);
  u16*   wInB  = (u16*)alloc((size_t)1536 * 768 * 2);
  u16*   wXpB  = (u16*)alloc((size_t)128 * 768 * 2);
  u16*   wDtB  = (u16*)alloc((size_t)768 * 64 * 2);
  u16*   wOutB = (u16*)alloc((size_t)768 * 768 * 2);
  float* aprod = (float*)alloc((size_t)NC * NCHAIN * 4);
  float* hend  = (float*)alloc((size_t)NC * NCHAIN * 4);
  float* carry = (float*)alloc((size_t)NC * NCHAIN * 4);

  cvt_pad_k<<<(1536 * 768 + 255) / 256, 256, 0, stream>>>(in_proj_w, wInB, 1536, 768, 768, 1536 * 768);
  cvt_pad_k<<<(128 * 768 + 255) / 256, 256, 0, stream>>>(x_proj_w, wXpB, 50, 768, 768, 128 * 768);
  cvt_pad_k<<<(768 * 64 + 255) / 256, 256, 0, stream>>>(dt_proj_w, wDtB, 768, 48, 64, 768 * 64);
  cvt_pad_k<<<(768 * 768 + 255) / 256, 256, 0, stream>>>(out_proj_w, wOutB, 768, 768, 768, 768 * 768);

  rmsnorm_k<<<TOK, 256, 0, stream>>>(x, rms_w, xnb);

  // xz = xn @ in_proj_w^T ; fused conv+silu -> xcb, silu(z) -> szb
  gemm_bt<1><<<dim3(1536 / 128, TOK / 128), 256, 0, stream>>>(
      xnb, DM, wInB, DM, DM, nullptr, 0, conv_w, conv_b, xcb, szb);

  // dbc = xc @ x_proj_w^T (N padded to 128); delta_raw -> dbcb bf16 (64 cols, zero pad), Bm/C -> bmc
  gemm_bt<3><<<dim3(1, TOK / 128), 256, 0, stream>>>(
      xcb, DM, wXpB, DM, DM, bmc, 2, nullptr, nullptr, dbcb, nullptr);

  // delta = softplus(delta_raw @ dt_proj_w^T + b)
  gemm_bt<2><<<dim3(768 / 128, TOK / 128), 256, 0, stream>>>(
      dbcb, 64, wDtB, 64, 64, delta, DM, dt_proj_b, nullptr, nullptr, nullptr);

  scan1_k<<<dim3(3, 8, NC), 256, 0, stream>>>(delta, xcb, bmc, A_log, aprod, hend);
  scan2_k<<<NCHAIN / 256, 256, 0, stream>>>(aprod, hend, carry);
  scan3_k<<<dim3(3, 8, NC), 256, 0, stream>>>(delta, xcb, bmc, A_log, Dp, szb, carry, ybf);

  // out = (y * silu(z)) @ out_proj_w^T
  gemm_bt<0><<<dim3(768 / 128, TOK / 128), 256, 0, stream>>>(
      ybf, DM, wOutB, DM, DM, out, DM, nullptr, nullptr, nullptr, nullptr);
}